// Round 15
// baseline (138.147 us; speedup 1.0000x reference)
//
#include <hip/hip_runtime.h>
#include <hip/hip_fp16.h>
#include <hip/hip_fp8.h>
#include <math.h>

#define HDIM   768
#define NSAMP  512
#define NLOG   513            // 1 target + 512 noise
#define VOCAB  50257
#define PADV   53248          // 1024 * 52, padded bin count for uint4 scan

// ---------------------------------------------------------------------------
// Sorted run-gather pipeline, fp8-h + depth-2 pipeline edition:
//  A) memsetAsync counts = 0
//  B) pre_kernel: fused {h -> packed fp8 e4m3 (192 u32/row)} + {histogram}
//  C) single-block exclusive scan over padded bins (uint4 in/out) -> cursor
//  D) scatter: counting sort, payload only (tok<<10 | slot)
//  E) gather-run: ONE WAVE PER VOCAB RUN, FOUR occurrence streams per
//     iteration, DEPTH-2 SOFTWARE PIPELINE (iteration j issues j+1's h
//     loads; payloads fetched 2 iterations ahead). W row EXACT fp32 in
//     registers. h unpacked with v_cvt_pk_f32_fp8 into 12 FMAs/occ.
//     Reduce: DPP row16 + ds_swizzle xor16 + shared shfl_xor(32).
//  F) per-token log-softmax + smoothed loss
//  G) deterministic mean
//
// NOTE: fp8 cvt builtins need the hi/word-select arg as a COMPILE-TIME
// constant (instruction immediate) -> helpers are templated on <HI>.
// ---------------------------------------------------------------------------

typedef float f32x2 __attribute__((ext_vector_type(2)));

// ---- fp8 e4m3 pack/unpack (HW builtins with header-type fallback) ----------
template <bool HI>
__device__ __forceinline__ f32x2 cvt2(unsigned u)
{
#if __has_builtin(__builtin_amdgcn_cvt_pk_f32_fp8)
    return __builtin_amdgcn_cvt_pk_f32_fp8((int)u, HI);
#else
    const unsigned s = HI ? (u >> 16) : u;
    __hip_fp8_e4m3 a, b;
    a.__x = (__hip_fp8_storage_t)(s & 0xffu);
    b.__x = (__hip_fp8_storage_t)((s >> 8) & 0xffu);
    f32x2 r; r[0] = (float)a; r[1] = (float)b; return r;
#endif
}

template <bool HI>
__device__ __forceinline__ unsigned pk8(float f0, float f1, unsigned old)
{
#if __has_builtin(__builtin_amdgcn_cvt_pk_fp8_f32)
    return (unsigned)__builtin_amdgcn_cvt_pk_fp8_f32(f0, f1, (int)old, HI);
#else
    __hip_fp8_e4m3 a(f0), b(f1);
    const unsigned v = (unsigned)a.__x | ((unsigned)b.__x << 8);
    return HI ? ((old & 0x0000ffffu) | (v << 16))
              : ((old & 0xffff0000u) | v);
#endif
}

// sum of all 16 lanes within each 16-lane row, via DPP row_ror adds (no DS)
__device__ __forceinline__ float row16_sum(float x)
{
    int t;
    t = __builtin_amdgcn_update_dpp(0, __float_as_int(x), 0x121, 0xF, 0xF, true);
    x += __int_as_float(t);    // + ror1
    t = __builtin_amdgcn_update_dpp(0, __float_as_int(x), 0x122, 0xF, 0xF, true);
    x += __int_as_float(t);    // + ror2
    t = __builtin_amdgcn_update_dpp(0, __float_as_int(x), 0x124, 0xF, 0xF, true);
    x += __int_as_float(t);    // + ror4
    t = __builtin_amdgcn_update_dpp(0, __float_as_int(x), 0x128, 0xF, 0xF, true);
    x += __int_as_float(t);    // + ror8
    return x;
}

// add xor-16 partner within each 32-lane half (one ds_swizzle)
__device__ __forceinline__ float xor16_add(float x)
{
    const int y = __builtin_amdgcn_ds_swizzle(__float_as_int(x), 0x401F);
    return x + __int_as_float(y);
}

#define CONVB 128          // blocks doing h conversion
#define HISTB 384          // blocks doing histogram
__global__ __launch_bounds__(256) void pre_kernel(
    const float* __restrict__ h, unsigned int* __restrict__ hb,
    const int* __restrict__ target, const int* __restrict__ noise,
    unsigned int* __restrict__ counts, int N, int nh8)
{
    if (blockIdx.x < CONVB) {
        // h -> fp8 e4m3, 4 elems per u32: hb[i] packs h[4i..4i+3]
        int i = blockIdx.x * 256 + threadIdx.x;
        const int stride = CONVB * 256;
        for (; i < nh8; i += stride) {
            const float4 p = reinterpret_cast<const float4*>(h)[i];
            unsigned u = pk8<false>(p.x, p.y, 0u);
            u = pk8<true>(p.z, p.w, u);
            hb[i] = u;
        }
    } else {
        int i = (blockIdx.x - CONVB) * 256 + threadIdx.x;
        const int stride = HISTB * 256;
        const int nn4 = (N * NSAMP) / 4;
        const int4* noise4 = reinterpret_cast<const int4*>(noise);
        for (int kk = i; kk < nn4; kk += stride) {
            const int4 vv = noise4[kk];
            atomicAdd(&counts[vv.x], 1u);
            atomicAdd(&counts[vv.y], 1u);
            atomicAdd(&counts[vv.z], 1u);
            atomicAdd(&counts[vv.w], 1u);
        }
        for (int kk = i; kk < N; kk += stride) atomicAdd(&counts[target[kk]], 1u);
    }
}

// single block, 1024 threads, 52 bins/thread, uint4 I/O (counts padded+zeroed)
__global__ __launch_bounds__(1024) void scan_kernel(
    const unsigned int* __restrict__ counts, unsigned int* __restrict__ cursor)
{
    const int tid = threadIdx.x;
    const uint4* c4 = reinterpret_cast<const uint4*>(counts) + tid * 13;
    uint4*      o4 = reinterpret_cast<uint4*>(cursor) + tid * 13;

    __shared__ unsigned int lds[1024];
    unsigned int s = 0;
    #pragma unroll
    for (int i = 0; i < 13; ++i) {
        const uint4 c = c4[i];
        s += c.x + c.y + c.z + c.w;
    }
    lds[tid] = s;
    __syncthreads();
    #pragma unroll
    for (int off = 1; off < 1024; off <<= 1) {
        unsigned int t = (tid >= off) ? lds[tid - off] : 0u;
        __syncthreads();
        lds[tid] += t;
        __syncthreads();
    }
    unsigned int run = (tid > 0) ? lds[tid - 1] : 0u;   // exclusive prefix
    #pragma unroll
    for (int i = 0; i < 13; ++i) {
        const uint4 c = c4[i];
        uint4 o;
        o.x = run;
        o.y = o.x + c.x;
        o.z = o.y + c.y;
        o.w = o.z + c.z;
        run = o.w + c.w;
        o4[i] = o;
    }
}

__global__ __launch_bounds__(256) void scatter_kernel(
    const int* __restrict__ target, const int* __restrict__ noise,
    unsigned int* __restrict__ cursor,
    unsigned int* __restrict__ sorted_pay, int N)
{
    int i = blockIdx.x * 256 + threadIdx.x;
    int stride = gridDim.x * 256;
    const int nn4 = (N * NSAMP) / 4;
    const int4* noise4 = reinterpret_cast<const int4*>(noise);
    for (int k = i; k < nn4; k += stride) {
        const int4 vv = noise4[k];
        const int kk = k * 4;
        #pragma unroll
        for (int j = 0; j < 4; ++j) {
            const int v    = (j == 0) ? vv.x : (j == 1) ? vv.y : (j == 2) ? vv.z : vv.w;
            const int idx  = kk + j;
            const int tok  = idx >> 9;            // /512
            const int slot = (idx & 511) + 1;     // noise -> slots 1..512
            const unsigned int pos = atomicAdd(&cursor[v], 1u);
            sorted_pay[pos] = ((unsigned int)tok << 10) | (unsigned int)slot;
        }
    }
    for (int k = i; k < N; k += stride) {
        const int v = target[k];
        const unsigned int pos = atomicAdd(&cursor[v], 1u);
        sorted_pay[pos] = ((unsigned int)k << 10);   // slot 0
    }
}

// one wave per vocab run; 4 occurrence streams/iter; depth-2 pipeline;
// fp8 h + fp32 W FMA
#define GTPB 256
__global__ __launch_bounds__(GTPB) void gather_run_kernel(
    const unsigned int* __restrict__ hb,          // fp8 h, 192 u32/row
    const float* __restrict__ W,
    const unsigned int* __restrict__ counts,
    const unsigned int* __restrict__ cursor,      // end offsets after scatter
    const unsigned int* __restrict__ sorted_pay,
    float* __restrict__ logits)
{
    const int v = blockIdx.x * (GTPB / 64) + (threadIdx.x >> 6);
    if (v >= VOCAB) return;
    const int cnt = (int)counts[v];
    if (cnt == 0) return;
    const int start = (int)cursor[v] - cnt;
    const int lane  = threadIdx.x & 63;
    const int last  = cnt - 1;

    // W row lane-slice, EXACT fp32, registers for the whole run.
    // Lane covers elems [8*lane, 8*lane+8) (a0,a1) and [512+4*lane, +4) (a2).
    const float4* wr = reinterpret_cast<const float4*>(W + (size_t)v * HDIM);
    const float4 a0 = wr[2 * lane], a1 = wr[2 * lane + 1], a2 = wr[128 + lane];

    const unsigned int* sp = sorted_pay + start;
    #define CLMP(k) ((k) < last ? (k) : last)

    const bool hi = lane >= 32;

    // payloads: current iteration (p0..p3) and next iteration (p4..p7)
    unsigned p0 = sp[0];
    unsigned p1 = sp[CLMP(1)];
    unsigned p2 = sp[CLMP(2)];
    unsigned p3 = sp[CLMP(3)];
    unsigned p4 = sp[CLMP(4)];
    unsigned p5 = sp[CLMP(5)];
    unsigned p6 = sp[CLMP(6)];
    unsigned p7 = sp[CLMP(7)];

    // issue iteration 0's h loads
    const unsigned* q0 = hb + (size_t)(p0 >> 10) * 192;
    const unsigned* q1 = hb + (size_t)(p1 >> 10) * 192;
    const unsigned* q2 = hb + (size_t)(p2 >> 10) * 192;
    const unsigned* q3 = hb + (size_t)(p3 >> 10) * 192;
    uint2    x0 = reinterpret_cast<const uint2*>(q0)[lane];
    unsigned y0 = q0[128 + lane];
    uint2    x1 = reinterpret_cast<const uint2*>(q1)[lane];
    unsigned y1 = q1[128 + lane];
    uint2    x2 = reinterpret_cast<const uint2*>(q2)[lane];
    unsigned y2 = q2[128 + lane];
    uint2    x3 = reinterpret_cast<const uint2*>(q3)[lane];
    unsigned y3 = q3[128 + lane];

    for (int j = 0; j < cnt; j += 4) {
        // issue NEXT iteration's h loads (depth-2 pipeline)
        const unsigned* n0 = hb + (size_t)(p4 >> 10) * 192;
        const unsigned* n1 = hb + (size_t)(p5 >> 10) * 192;
        const unsigned* n2 = hb + (size_t)(p6 >> 10) * 192;
        const unsigned* n3 = hb + (size_t)(p7 >> 10) * 192;
        const uint2    nx0 = reinterpret_cast<const uint2*>(n0)[lane];
        const unsigned ny0 = n0[128 + lane];
        const uint2    nx1 = reinterpret_cast<const uint2*>(n1)[lane];
        const unsigned ny1 = n1[128 + lane];
        const uint2    nx2 = reinterpret_cast<const uint2*>(n2)[lane];
        const unsigned ny2 = n2[128 + lane];
        const uint2    nx3 = reinterpret_cast<const uint2*>(n3)[lane];
        const unsigned ny3 = n3[128 + lane];

        // fetch payloads 2 iterations ahead
        const unsigned f0 = sp[CLMP(j + 8)];
        const unsigned f1 = sp[CLMP(j + 9)];
        const unsigned f2 = sp[CLMP(j + 10)];
        const unsigned f3 = sp[CLMP(j + 11)];

        // compute current iteration: 6 cvt + 12 FMA per occurrence (2 chains)
        float s0a, s0b, s1a, s1b, s2a, s2b, s3a, s3b;
        {
            f32x2 p;
            p = cvt2<false>(x0.x); s0a = p[0]*a0.x + p[1]*a0.y;
            p = cvt2<true >(x0.x); s0b = p[0]*a0.z + p[1]*a0.w;
            p = cvt2<false>(x0.y); s0a = fmaf(p[0], a1.x, fmaf(p[1], a1.y, s0a));
            p = cvt2<true >(x0.y); s0b = fmaf(p[0], a1.z, fmaf(p[1], a1.w, s0b));
            p = cvt2<false>(y0);   s0a = fmaf(p[0], a2.x, fmaf(p[1], a2.y, s0a));
            p = cvt2<true >(y0);   s0b = fmaf(p[0], a2.z, fmaf(p[1], a2.w, s0b));
        }
        {
            f32x2 p;
            p = cvt2<false>(x1.x); s1a = p[0]*a0.x + p[1]*a0.y;
            p = cvt2<true >(x1.x); s1b = p[0]*a0.z + p[1]*a0.w;
            p = cvt2<false>(x1.y); s1a = fmaf(p[0], a1.x, fmaf(p[1], a1.y, s1a));
            p = cvt2<true >(x1.y); s1b = fmaf(p[0], a1.z, fmaf(p[1], a1.w, s1b));
            p = cvt2<false>(y1);   s1a = fmaf(p[0], a2.x, fmaf(p[1], a2.y, s1a));
            p = cvt2<true >(y1);   s1b = fmaf(p[0], a2.z, fmaf(p[1], a2.w, s1b));
        }
        {
            f32x2 p;
            p = cvt2<false>(x2.x); s2a = p[0]*a0.x + p[1]*a0.y;
            p = cvt2<true >(x2.x); s2b = p[0]*a0.z + p[1]*a0.w;
            p = cvt2<false>(x2.y); s2a = fmaf(p[0], a1.x, fmaf(p[1], a1.y, s2a));
            p = cvt2<true >(x2.y); s2b = fmaf(p[0], a1.z, fmaf(p[1], a1.w, s2b));
            p = cvt2<false>(y2);   s2a = fmaf(p[0], a2.x, fmaf(p[1], a2.y, s2a));
            p = cvt2<true >(y2);   s2b = fmaf(p[0], a2.z, fmaf(p[1], a2.w, s2b));
        }
        {
            f32x2 p;
            p = cvt2<false>(x3.x); s3a = p[0]*a0.x + p[1]*a0.y;
            p = cvt2<true >(x3.x); s3b = p[0]*a0.z + p[1]*a0.w;
            p = cvt2<false>(x3.y); s3a = fmaf(p[0], a1.x, fmaf(p[1], a1.y, s3a));
            p = cvt2<true >(x3.y); s3b = fmaf(p[0], a1.z, fmaf(p[1], a1.w, s3b));
            p = cvt2<false>(y3);   s3a = fmaf(p[0], a2.x, fmaf(p[1], a2.y, s3a));
            p = cvt2<true >(y3);   s3b = fmaf(p[0], a2.z, fmaf(p[1], a2.w, s3b));
        }
        float s0 = s0a + s0b, s1 = s1a + s1b;
        float s2 = s2a + s2b, s3 = s3a + s3b;

        // reduce: 4 interleaved DPP/swizzle chains, 2 shared shfl_xor(32)
        s0 = xor16_add(row16_sum(s0));
        s1 = xor16_add(row16_sum(s1));
        s2 = xor16_add(row16_sum(s2));
        s3 = xor16_add(row16_sum(s3));
        float cA = hi ? s1 : s0;
        float dA = hi ? s0 : s1;
        cA += __shfl_xor(dA, 32, 64);    // lo: S0 | hi: S1
        float cB = hi ? s3 : s2;
        float dB = hi ? s2 : s3;
        cB += __shfl_xor(dB, 32, 64);    // lo: S2 | hi: S3

        if (lane == 0) {
            logits[(size_t)(p0 >> 10) * NLOG + (p0 & 1023u)] = cA;
            if (j + 2 < cnt)
                logits[(size_t)(p2 >> 10) * NLOG + (p2 & 1023u)] = cB;
        } else if (lane == 32) {
            if (j + 1 < cnt)
                logits[(size_t)(p1 >> 10) * NLOG + (p1 & 1023u)] = cA;
            if (j + 3 < cnt)
                logits[(size_t)(p3 >> 10) * NLOG + (p3 & 1023u)] = cB;
        }

        // rotate pipeline
        p0 = p4; p1 = p5; p2 = p6; p3 = p7;
        p4 = f0; p5 = f1; p6 = f2; p7 = f3;
        x0 = nx0; y0 = ny0; x1 = nx1; y1 = ny1;
        x2 = nx2; y2 = ny2; x3 = nx3; y3 = ny3;
    }
    #undef CLMP
}

__global__ __launch_bounds__(256) void softmax_loss_kernel(
    const float* __restrict__ logits, float* __restrict__ loss_per_token)
{
    const int n    = blockIdx.x;
    const int tid  = threadIdx.x;
    const int lane = tid & 63;
    const int wave = tid >> 6;
    const float* row = logits + (size_t)n * NLOG;

    __shared__ float red[4];
    __shared__ float red2[4][2];

    float lmax = -INFINITY;
    for (int r = tid; r < NLOG; r += 256) lmax = fmaxf(lmax, row[r]);
    #pragma unroll
    for (int off = 32; off; off >>= 1) lmax = fmaxf(lmax, __shfl_xor(lmax, off, 64));
    if (lane == 0) red[wave] = lmax;
    __syncthreads();
    lmax = fmaxf(fmaxf(red[0], red[1]), fmaxf(red[2], red[3]));

    float esum = 0.f, lsum = 0.f;
    for (int r = tid; r < NLOG; r += 256) {
        const float l = row[r];
        esum += __expf(l - lmax);
        if (r > 0) lsum += l;
    }
    #pragma unroll
    for (int off = 32; off; off >>= 1) {
        esum += __shfl_xor(esum, off, 64);
        lsum += __shfl_xor(lsum, off, 64);
    }
    if (lane == 0) { red2[wave][0] = esum; red2[wave][1] = lsum; }
    __syncthreads();

    if (tid == 0) {
        esum = red2[0][0] + red2[1][0] + red2[2][0] + red2[3][0];
        lsum = red2[0][1] + red2[1][1] + red2[2][1] + red2[3][1];
        const float lse  = lmax + logf(esum);
        const float l0   = row[0];
        const float loss = -0.9f * (l0 - lse)
                         - (0.1f / 512.f) * (lsum - 512.f * lse);
        loss_per_token[n] = loss;
    }
}

__global__ __launch_bounds__(256) void reduce_mean_kernel(
    const float* __restrict__ x, float* __restrict__ out, int n)
{
    const int tid = threadIdx.x;
    float s = 0.f;
    for (int i = tid; i < n; i += 256) s += x[i];
    #pragma unroll
    for (int off = 32; off; off >>= 1) s += __shfl_xor(s, off, 64);
    __shared__ float red[4];
    if ((tid & 63) == 0) red[tid >> 6] = s;
    __syncthreads();
    if (tid == 0) out[0] = (red[0] + red[1] + red[2] + red[3]) / (float)n;
}

// ------------------------- legacy fallback (R1) ----------------------------
__global__ __launch_bounds__(512) void nce_token_kernel(
    const float* __restrict__ h, const float* __restrict__ W,
    const int* __restrict__ target, const int* __restrict__ noise,
    float* __restrict__ loss_per_token)
{
    const int n    = blockIdx.x;
    const int tid  = threadIdx.x;
    const int lane = tid & 63;
    const int wave = tid >> 6;

    __shared__ float  logits[NLOG];
    __shared__ float4 hsm[HDIM / 4];
    __shared__ float  red[8];
    __shared__ float  red2[8][2];

    const float4* hrow = reinterpret_cast<const float4*>(h + (size_t)n * HDIM);
    if (tid < HDIM / 4) hsm[tid] = hrow[tid];
    __syncthreads();

    const float4 h0 = hsm[lane];
    const float4 h1 = hsm[lane + 64];
    const float4 h2 = hsm[lane + 128];
    const int* nrow = noise + (size_t)n * NSAMP;

    for (int r = wave; r < NLOG; r += 8) {
        const int row = (r == 0) ? target[n] : nrow[r - 1];
        const float4* wr = reinterpret_cast<const float4*>(W + (size_t)row * HDIM);
        const float4 w0 = wr[lane];
        const float4 w1 = wr[lane + 64];
        const float4 w2 = wr[lane + 128];
        float s;
        s  = h0.x * w0.x + h0.y * w0.y + h0.z * w0.z + h0.w * w0.w;
        s += h1.x * w1.x + h1.y * w1.y + h1.z * w1.z + h1.w * w1.w;
        s += h2.x * w2.x + h2.y * w2.y + h2.z * w2.z + h2.w * w2.w;
        #pragma unroll
        for (int off = 32; off; off >>= 1) s += __shfl_xor(s, off, 64);
        if (lane == 0) logits[r] = s;
    }
    __syncthreads();

    float lmax = -INFINITY;
    for (int r = tid; r < NLOG; r += 512) lmax = fmaxf(lmax, logits[r]);
    #pragma unroll
    for (int off = 32; off; off >>= 1) lmax = fmaxf(lmax, __shfl_xor(lmax, off, 64));
    if (lane == 0) red[wave] = lmax;
    __syncthreads();
    if (wave == 0) {
        float m = (lane < 8) ? red[lane] : -INFINITY;
        #pragma unroll
        for (int off = 4; off; off >>= 1) m = fmaxf(m, __shfl_xor(m, off, 64));
        if (lane == 0) red[0] = m;
    }
    __syncthreads();
    lmax = red[0];

    float esum = 0.f, lsum = 0.f;
    for (int r = tid; r < NLOG; r += 512) {
        const float l = logits[r];
        esum += __expf(l - lmax);
        if (r > 0) lsum += l;
    }
    #pragma unroll
    for (int off = 32; off; off >>= 1) {
        esum += __shfl_xor(esum, off, 64);
        lsum += __shfl_xor(lsum, off, 64);
    }
    if (lane == 0) { red2[wave][0] = esum; red2[wave][1] = lsum; }
    __syncthreads();

    if (tid == 0) {
        esum = 0.f; lsum = 0.f;
        #pragma unroll
        for (int w = 0; w < 8; ++w) { esum += red2[w][0]; lsum += red2[w][1]; }
        const float lse  = lmax + logf(esum);
        const float loss = -0.9f * (logits[0] - lse)
                         - (0.1f / 512.f) * (lsum - 512.f * lse);
        loss_per_token[n] = loss;
    }
}
// ---------------------------------------------------------------------------

extern "C" void kernel_launch(void* const* d_in, const int* in_sizes, int n_in,
                              void* d_out, int out_size, void* d_ws, size_t ws_size,
                              hipStream_t stream)
{
    const float* h      = (const float*)d_in[0];   // [N, 768] fp32
    const float* W      = (const float*)d_in[1];   // [50257, 768] fp32
    const int*   target = (const int*)d_in[2];     // [N] int32
    const int*   noise  = (const int*)d_in[3];     // [N, 512] int32
    float*       out    = (float*)d_out;
    const int    N      = in_sizes[2];             // 1024 tokens
    const int    nocc   = N * NLOG;                // 525312
    const int    nh8    = N * HDIM / 4;            // 196608 packed fp8 u32

    // ws layout (u32/f32 elements): counts[PADV] cursor[PADV] pay[nocc]
    //                               hb[nh8] logits[nocc] loss[N]
    unsigned int* counts     = (unsigned int*)d_ws;
    unsigned int* cursor     = counts + PADV;
    unsigned int* sorted_pay = cursor + PADV;
    unsigned int* hb         = sorted_pay + nocc;
    float*        logits     = (float*)(hb + nh8);
    float*        loss       = logits + nocc;
    const size_t  need_bytes = (size_t)(2 * PADV + 2 * nocc + nh8 + N) * 4;

    if (ws_size < need_bytes) {
        // fallback: direct gather path (R1)
        float* ws = (float*)d_ws;
        nce_token_kernel<<<N, 512, 0, stream>>>(h, W, target, noise, ws);
        reduce_mean_kernel<<<1, 256, 0, stream>>>(ws, out, N);
        return;
    }

    (void)hipMemsetAsync(counts, 0, (size_t)PADV * 4, stream);
    pre_kernel<<<CONVB + HISTB, 256, 0, stream>>>(h, hb, target, noise,
                                                  counts, N, nh8);
    scan_kernel<<<1, 1024, 0, stream>>>(counts, cursor);
    scatter_kernel<<<512, 256, 0, stream>>>(target, noise, cursor, sorted_pay, N);
    const int gblocks = (VOCAB + (GTPB / 64) - 1) / (GTPB / 64);
    gather_run_kernel<<<gblocks, GTPB, 0, stream>>>(hb, W, counts, cursor,
                                                    sorted_pay, logits);
    softmax_loss_kernel<<<N, 256, 0, stream>>>(logits, loss);
    reduce_mean_kernel<<<1, 256, 0, stream>>>(loss, out, N);
}

// Round 16
// 131.732 us; speedup vs baseline: 1.0487x; 1.0487x over previous
//
#include <hip/hip_runtime.h>
#include <hip/hip_fp16.h>
#include <hip/hip_fp8.h>
#include <math.h>

#define HDIM   768
#define NSAMP  512
#define NLOG   513            // 1 target + 512 noise
#define VOCAB  50257
#define PADV   53248          // 1024 * 52, padded bin count for uint4 scan

// ---------------------------------------------------------------------------
// Sorted run-gather pipeline, fp8-h edition (best measured: 131.9 us):
//  A) memsetAsync counts = 0
//  B) pre_kernel: fused {h -> packed fp8 e4m3 (192 u32/row)} + {histogram}
//  C) single-block exclusive scan over padded bins (uint4 in/out) -> cursor
//  D) scatter: counting sort, payload only (tok<<10 | slot)
//  E) gather-run: ONE WAVE PER VOCAB RUN, FOUR occurrence streams per
//     iteration (8 VMEM instrs, 12 lines/occ). W row EXACT fp32 in
//     registers. h unpacked with v_cvt_pk_f32_fp8 into 12 FMAs/occ.
//     Reduce: DPP row16 + ds_swizzle xor16 + shared shfl_xor(32).
//  F) per-token log-softmax + smoothed loss
//  G) deterministic mean
//
// NOTE: fp8 cvt builtins need the hi/word-select arg as a COMPILE-TIME
// constant (instruction immediate) -> helpers are templated on <HI>.
// ---------------------------------------------------------------------------

typedef float f32x2 __attribute__((ext_vector_type(2)));

// ---- fp8 e4m3 pack/unpack (HW builtins with header-type fallback) ----------
template <bool HI>
__device__ __forceinline__ f32x2 cvt2(unsigned u)
{
#if __has_builtin(__builtin_amdgcn_cvt_pk_f32_fp8)
    return __builtin_amdgcn_cvt_pk_f32_fp8((int)u, HI);
#else
    const unsigned s = HI ? (u >> 16) : u;
    __hip_fp8_e4m3 a, b;
    a.__x = (__hip_fp8_storage_t)(s & 0xffu);
    b.__x = (__hip_fp8_storage_t)((s >> 8) & 0xffu);
    f32x2 r; r[0] = (float)a; r[1] = (float)b; return r;
#endif
}

template <bool HI>
__device__ __forceinline__ unsigned pk8(float f0, float f1, unsigned old)
{
#if __has_builtin(__builtin_amdgcn_cvt_pk_fp8_f32)
    return (unsigned)__builtin_amdgcn_cvt_pk_fp8_f32(f0, f1, (int)old, HI);
#else
    __hip_fp8_e4m3 a(f0), b(f1);
    const unsigned v = (unsigned)a.__x | ((unsigned)b.__x << 8);
    return HI ? ((old & 0x0000ffffu) | (v << 16))
              : ((old & 0xffff0000u) | v);
#endif
}

// sum of all 16 lanes within each 16-lane row, via DPP row_ror adds (no DS)
__device__ __forceinline__ float row16_sum(float x)
{
    int t;
    t = __builtin_amdgcn_update_dpp(0, __float_as_int(x), 0x121, 0xF, 0xF, true);
    x += __int_as_float(t);    // + ror1
    t = __builtin_amdgcn_update_dpp(0, __float_as_int(x), 0x122, 0xF, 0xF, true);
    x += __int_as_float(t);    // + ror2
    t = __builtin_amdgcn_update_dpp(0, __float_as_int(x), 0x124, 0xF, 0xF, true);
    x += __int_as_float(t);    // + ror4
    t = __builtin_amdgcn_update_dpp(0, __float_as_int(x), 0x128, 0xF, 0xF, true);
    x += __int_as_float(t);    // + ror8
    return x;
}

// add xor-16 partner within each 32-lane half (one ds_swizzle)
__device__ __forceinline__ float xor16_add(float x)
{
    const int y = __builtin_amdgcn_ds_swizzle(__float_as_int(x), 0x401F);
    return x + __int_as_float(y);
}

#define CONVB 128          // blocks doing h conversion
#define HISTB 384          // blocks doing histogram
__global__ __launch_bounds__(256) void pre_kernel(
    const float* __restrict__ h, unsigned int* __restrict__ hb,
    const int* __restrict__ target, const int* __restrict__ noise,
    unsigned int* __restrict__ counts, int N, int nh8)
{
    if (blockIdx.x < CONVB) {
        // h -> fp8 e4m3, 4 elems per u32: hb[i] packs h[4i..4i+3]
        int i = blockIdx.x * 256 + threadIdx.x;
        const int stride = CONVB * 256;
        for (; i < nh8; i += stride) {
            const float4 p = reinterpret_cast<const float4*>(h)[i];
            unsigned u = pk8<false>(p.x, p.y, 0u);
            u = pk8<true>(p.z, p.w, u);
            hb[i] = u;
        }
    } else {
        int i = (blockIdx.x - CONVB) * 256 + threadIdx.x;
        const int stride = HISTB * 256;
        const int nn4 = (N * NSAMP) / 4;
        const int4* noise4 = reinterpret_cast<const int4*>(noise);
        for (int kk = i; kk < nn4; kk += stride) {
            const int4 vv = noise4[kk];
            atomicAdd(&counts[vv.x], 1u);
            atomicAdd(&counts[vv.y], 1u);
            atomicAdd(&counts[vv.z], 1u);
            atomicAdd(&counts[vv.w], 1u);
        }
        for (int kk = i; kk < N; kk += stride) atomicAdd(&counts[target[kk]], 1u);
    }
}

// single block, 1024 threads, 52 bins/thread, uint4 I/O (counts padded+zeroed)
__global__ __launch_bounds__(1024) void scan_kernel(
    const unsigned int* __restrict__ counts, unsigned int* __restrict__ cursor)
{
    const int tid = threadIdx.x;
    const uint4* c4 = reinterpret_cast<const uint4*>(counts) + tid * 13;
    uint4*      o4 = reinterpret_cast<uint4*>(cursor) + tid * 13;

    __shared__ unsigned int lds[1024];
    unsigned int s = 0;
    #pragma unroll
    for (int i = 0; i < 13; ++i) {
        const uint4 c = c4[i];
        s += c.x + c.y + c.z + c.w;
    }
    lds[tid] = s;
    __syncthreads();
    #pragma unroll
    for (int off = 1; off < 1024; off <<= 1) {
        unsigned int t = (tid >= off) ? lds[tid - off] : 0u;
        __syncthreads();
        lds[tid] += t;
        __syncthreads();
    }
    unsigned int run = (tid > 0) ? lds[tid - 1] : 0u;   // exclusive prefix
    #pragma unroll
    for (int i = 0; i < 13; ++i) {
        const uint4 c = c4[i];
        uint4 o;
        o.x = run;
        o.y = o.x + c.x;
        o.z = o.y + c.y;
        o.w = o.z + c.z;
        run = o.w + c.w;
        o4[i] = o;
    }
}

__global__ __launch_bounds__(256) void scatter_kernel(
    const int* __restrict__ target, const int* __restrict__ noise,
    unsigned int* __restrict__ cursor,
    unsigned int* __restrict__ sorted_pay, int N)
{
    int i = blockIdx.x * 256 + threadIdx.x;
    int stride = gridDim.x * 256;
    const int nn4 = (N * NSAMP) / 4;
    const int4* noise4 = reinterpret_cast<const int4*>(noise);
    for (int k = i; k < nn4; k += stride) {
        const int4 vv = noise4[k];
        const int kk = k * 4;
        #pragma unroll
        for (int j = 0; j < 4; ++j) {
            const int v    = (j == 0) ? vv.x : (j == 1) ? vv.y : (j == 2) ? vv.z : vv.w;
            const int idx  = kk + j;
            const int tok  = idx >> 9;            // /512
            const int slot = (idx & 511) + 1;     // noise -> slots 1..512
            const unsigned int pos = atomicAdd(&cursor[v], 1u);
            sorted_pay[pos] = ((unsigned int)tok << 10) | (unsigned int)slot;
        }
    }
    for (int k = i; k < N; k += stride) {
        const int v = target[k];
        const unsigned int pos = atomicAdd(&cursor[v], 1u);
        sorted_pay[pos] = ((unsigned int)k << 10);   // slot 0
    }
}

// one wave per vocab run; 4 occurrence streams/iter; fp8 h + fp32 W FMA
#define GTPB 256
__global__ __launch_bounds__(GTPB) void gather_run_kernel(
    const unsigned int* __restrict__ hb,          // fp8 h, 192 u32/row
    const float* __restrict__ W,
    const unsigned int* __restrict__ counts,
    const unsigned int* __restrict__ cursor,      // end offsets after scatter
    const unsigned int* __restrict__ sorted_pay,
    float* __restrict__ logits)
{
    const int v = blockIdx.x * (GTPB / 64) + (threadIdx.x >> 6);
    if (v >= VOCAB) return;
    const int cnt = (int)counts[v];
    if (cnt == 0) return;
    const int start = (int)cursor[v] - cnt;
    const int lane  = threadIdx.x & 63;
    const int last  = cnt - 1;

    // W row lane-slice, EXACT fp32, registers for the whole run.
    // Lane covers elems [8*lane, 8*lane+8) (a0,a1) and [512+4*lane, +4) (a2).
    const float4* wr = reinterpret_cast<const float4*>(W + (size_t)v * HDIM);
    const float4 a0 = wr[2 * lane], a1 = wr[2 * lane + 1], a2 = wr[128 + lane];

    const unsigned int* sp = sorted_pay + start;
    #define CLMP(k) ((k) < last ? (k) : last)

    const bool hi = lane >= 32;

    // payloads for iteration 0
    unsigned pay0 = sp[0];
    unsigned pay1 = sp[CLMP(1)];
    unsigned pay2 = sp[CLMP(2)];
    unsigned pay3 = sp[CLMP(3)];

    for (int j = 0; j < cnt; j += 4) {
        // issue 8 h loads for the 4 current streams (12 lines/occ)
        const unsigned* r0 = hb + (size_t)(pay0 >> 10) * 192;
        const unsigned* r1 = hb + (size_t)(pay1 >> 10) * 192;
        const unsigned* r2 = hb + (size_t)(pay2 >> 10) * 192;
        const unsigned* r3 = hb + (size_t)(pay3 >> 10) * 192;
        const uint2 x0 = reinterpret_cast<const uint2*>(r0)[lane];
        const unsigned y0 = r0[128 + lane];
        const uint2 x1 = reinterpret_cast<const uint2*>(r1)[lane];
        const unsigned y1 = r1[128 + lane];
        const uint2 x2 = reinterpret_cast<const uint2*>(r2)[lane];
        const unsigned y2 = r2[128 + lane];
        const uint2 x3 = reinterpret_cast<const uint2*>(r3)[lane];
        const unsigned y3 = r3[128 + lane];

        // prefetch next iteration's payloads while loads fly
        const unsigned np0 = sp[CLMP(j + 4)];
        const unsigned np1 = sp[CLMP(j + 5)];
        const unsigned np2 = sp[CLMP(j + 6)];
        const unsigned np3 = sp[CLMP(j + 7)];

        // four occurrences: 6 cvt_pk_f32_fp8 + 12 fp32 FMA each (2 chains)
        float s0a, s0b, s1a, s1b, s2a, s2b, s3a, s3b;
        {
            f32x2 p;
            p = cvt2<false>(x0.x); s0a = p[0]*a0.x + p[1]*a0.y;
            p = cvt2<true >(x0.x); s0b = p[0]*a0.z + p[1]*a0.w;
            p = cvt2<false>(x0.y); s0a = fmaf(p[0], a1.x, fmaf(p[1], a1.y, s0a));
            p = cvt2<true >(x0.y); s0b = fmaf(p[0], a1.z, fmaf(p[1], a1.w, s0b));
            p = cvt2<false>(y0);   s0a = fmaf(p[0], a2.x, fmaf(p[1], a2.y, s0a));
            p = cvt2<true >(y0);   s0b = fmaf(p[0], a2.z, fmaf(p[1], a2.w, s0b));
        }
        {
            f32x2 p;
            p = cvt2<false>(x1.x); s1a = p[0]*a0.x + p[1]*a0.y;
            p = cvt2<true >(x1.x); s1b = p[0]*a0.z + p[1]*a0.w;
            p = cvt2<false>(x1.y); s1a = fmaf(p[0], a1.x, fmaf(p[1], a1.y, s1a));
            p = cvt2<true >(x1.y); s1b = fmaf(p[0], a1.z, fmaf(p[1], a1.w, s1b));
            p = cvt2<false>(y1);   s1a = fmaf(p[0], a2.x, fmaf(p[1], a2.y, s1a));
            p = cvt2<true >(y1);   s1b = fmaf(p[0], a2.z, fmaf(p[1], a2.w, s1b));
        }
        {
            f32x2 p;
            p = cvt2<false>(x2.x); s2a = p[0]*a0.x + p[1]*a0.y;
            p = cvt2<true >(x2.x); s2b = p[0]*a0.z + p[1]*a0.w;
            p = cvt2<false>(x2.y); s2a = fmaf(p[0], a1.x, fmaf(p[1], a1.y, s2a));
            p = cvt2<true >(x2.y); s2b = fmaf(p[0], a1.z, fmaf(p[1], a1.w, s2b));
            p = cvt2<false>(y2);   s2a = fmaf(p[0], a2.x, fmaf(p[1], a2.y, s2a));
            p = cvt2<true >(y2);   s2b = fmaf(p[0], a2.z, fmaf(p[1], a2.w, s2b));
        }
        {
            f32x2 p;
            p = cvt2<false>(x3.x); s3a = p[0]*a0.x + p[1]*a0.y;
            p = cvt2<true >(x3.x); s3b = p[0]*a0.z + p[1]*a0.w;
            p = cvt2<false>(x3.y); s3a = fmaf(p[0], a1.x, fmaf(p[1], a1.y, s3a));
            p = cvt2<true >(x3.y); s3b = fmaf(p[0], a1.z, fmaf(p[1], a1.w, s3b));
            p = cvt2<false>(y3);   s3a = fmaf(p[0], a2.x, fmaf(p[1], a2.y, s3a));
            p = cvt2<true >(y3);   s3b = fmaf(p[0], a2.z, fmaf(p[1], a2.w, s3b));
        }
        float s0 = s0a + s0b, s1 = s1a + s1b;
        float s2 = s2a + s2b, s3 = s3a + s3b;

        // reduce: 4 interleaved DPP/swizzle chains, 2 shared shfl_xor(32)
        s0 = xor16_add(row16_sum(s0));
        s1 = xor16_add(row16_sum(s1));
        s2 = xor16_add(row16_sum(s2));
        s3 = xor16_add(row16_sum(s3));
        float cA = hi ? s1 : s0;
        float dA = hi ? s0 : s1;
        cA += __shfl_xor(dA, 32, 64);    // lo: S0 | hi: S1
        float cB = hi ? s3 : s2;
        float dB = hi ? s2 : s3;
        cB += __shfl_xor(dB, 32, 64);    // lo: S2 | hi: S3

        if (lane == 0) {
            logits[(size_t)(pay0 >> 10) * NLOG + (pay0 & 1023u)] = cA;
            if (j + 2 < cnt)
                logits[(size_t)(pay2 >> 10) * NLOG + (pay2 & 1023u)] = cB;
        } else if (lane == 32) {
            if (j + 1 < cnt)
                logits[(size_t)(pay1 >> 10) * NLOG + (pay1 & 1023u)] = cA;
            if (j + 3 < cnt)
                logits[(size_t)(pay3 >> 10) * NLOG + (pay3 & 1023u)] = cB;
        }

        pay0 = np0; pay1 = np1; pay2 = np2; pay3 = np3;
    }
    #undef CLMP
}

__global__ __launch_bounds__(256) void softmax_loss_kernel(
    const float* __restrict__ logits, float* __restrict__ loss_per_token)
{
    const int n    = blockIdx.x;
    const int tid  = threadIdx.x;
    const int lane = tid & 63;
    const int wave = tid >> 6;
    const float* row = logits + (size_t)n * NLOG;

    __shared__ float red[4];
    __shared__ float red2[4][2];

    float lmax = -INFINITY;
    for (int r = tid; r < NLOG; r += 256) lmax = fmaxf(lmax, row[r]);
    #pragma unroll
    for (int off = 32; off; off >>= 1) lmax = fmaxf(lmax, __shfl_xor(lmax, off, 64));
    if (lane == 0) red[wave] = lmax;
    __syncthreads();
    lmax = fmaxf(fmaxf(red[0], red[1]), fmaxf(red[2], red[3]));

    float esum = 0.f, lsum = 0.f;
    for (int r = tid; r < NLOG; r += 256) {
        const float l = row[r];
        esum += __expf(l - lmax);
        if (r > 0) lsum += l;
    }
    #pragma unroll
    for (int off = 32; off; off >>= 1) {
        esum += __shfl_xor(esum, off, 64);
        lsum += __shfl_xor(lsum, off, 64);
    }
    if (lane == 0) { red2[wave][0] = esum; red2[wave][1] = lsum; }
    __syncthreads();

    if (tid == 0) {
        esum = red2[0][0] + red2[1][0] + red2[2][0] + red2[3][0];
        lsum = red2[0][1] + red2[1][1] + red2[2][1] + red2[3][1];
        const float lse  = lmax + logf(esum);
        const float l0   = row[0];
        const float loss = -0.9f * (l0 - lse)
                         - (0.1f / 512.f) * (lsum - 512.f * lse);
        loss_per_token[n] = loss;
    }
}

__global__ __launch_bounds__(256) void reduce_mean_kernel(
    const float* __restrict__ x, float* __restrict__ out, int n)
{
    const int tid = threadIdx.x;
    float s = 0.f;
    for (int i = tid; i < n; i += 256) s += x[i];
    #pragma unroll
    for (int off = 32; off; off >>= 1) s += __shfl_xor(s, off, 64);
    __shared__ float red[4];
    if ((tid & 63) == 0) red[tid >> 6] = s;
    __syncthreads();
    if (tid == 0) out[0] = (red[0] + red[1] + red[2] + red[3]) / (float)n;
}

// ------------------------- legacy fallback (R1) ----------------------------
__global__ __launch_bounds__(512) void nce_token_kernel(
    const float* __restrict__ h, const float* __restrict__ W,
    const int* __restrict__ target, const int* __restrict__ noise,
    float* __restrict__ loss_per_token)
{
    const int n    = blockIdx.x;
    const int tid  = threadIdx.x;
    const int lane = tid & 63;
    const int wave = tid >> 6;

    __shared__ float  logits[NLOG];
    __shared__ float4 hsm[HDIM / 4];
    __shared__ float  red[8];
    __shared__ float  red2[8][2];

    const float4* hrow = reinterpret_cast<const float4*>(h + (size_t)n * HDIM);
    if (tid < HDIM / 4) hsm[tid] = hrow[tid];
    __syncthreads();

    const float4 h0 = hsm[lane];
    const float4 h1 = hsm[lane + 64];
    const float4 h2 = hsm[lane + 128];
    const int* nrow = noise + (size_t)n * NSAMP;

    for (int r = wave; r < NLOG; r += 8) {
        const int row = (r == 0) ? target[n] : nrow[r - 1];
        const float4* wr = reinterpret_cast<const float4*>(W + (size_t)row * HDIM);
        const float4 w0 = wr[lane];
        const float4 w1 = wr[lane + 64];
        const float4 w2 = wr[lane + 128];
        float s;
        s  = h0.x * w0.x + h0.y * w0.y + h0.z * w0.z + h0.w * w0.w;
        s += h1.x * w1.x + h1.y * w1.y + h1.z * w1.z + h1.w * w1.w;
        s += h2.x * w2.x + h2.y * w2.y + h2.z * w2.z + h2.w * w2.w;
        #pragma unroll
        for (int off = 32; off; off >>= 1) s += __shfl_xor(s, off, 64);
        if (lane == 0) logits[r] = s;
    }
    __syncthreads();

    float lmax = -INFINITY;
    for (int r = tid; r < NLOG; r += 512) lmax = fmaxf(lmax, logits[r]);
    #pragma unroll
    for (int off = 32; off; off >>= 1) lmax = fmaxf(lmax, __shfl_xor(lmax, off, 64));
    if (lane == 0) red[wave] = lmax;
    __syncthreads();
    if (wave == 0) {
        float m = (lane < 8) ? red[lane] : -INFINITY;
        #pragma unroll
        for (int off = 4; off; off >>= 1) m = fmaxf(m, __shfl_xor(m, off, 64));
        if (lane == 0) red[0] = m;
    }
    __syncthreads();
    lmax = red[0];

    float esum = 0.f, lsum = 0.f;
    for (int r = tid; r < NLOG; r += 512) {
        const float l = logits[r];
        esum += __expf(l - lmax);
        if (r > 0) lsum += l;
    }
    #pragma unroll
    for (int off = 32; off; off >>= 1) {
        esum += __shfl_xor(esum, off, 64);
        lsum += __shfl_xor(lsum, off, 64);
    }
    if (lane == 0) { red2[wave][0] = esum; red2[wave][1] = lsum; }
    __syncthreads();

    if (tid == 0) {
        esum = 0.f; lsum = 0.f;
        #pragma unroll
        for (int w = 0; w < 8; ++w) { esum += red2[w][0]; lsum += red2[w][1]; }
        const float lse  = lmax + logf(esum);
        const float loss = -0.9f * (logits[0] - lse)
                         - (0.1f / 512.f) * (lsum - 512.f * lse);
        loss_per_token[n] = loss;
    }
}
// ---------------------------------------------------------------------------

extern "C" void kernel_launch(void* const* d_in, const int* in_sizes, int n_in,
                              void* d_out, int out_size, void* d_ws, size_t ws_size,
                              hipStream_t stream)
{
    const float* h      = (const float*)d_in[0];   // [N, 768] fp32
    const float* W      = (const float*)d_in[1];   // [50257, 768] fp32
    const int*   target = (const int*)d_in[2];     // [N] int32
    const int*   noise  = (const int*)d_in[3];     // [N, 512] int32
    float*       out    = (float*)d_out;
    const int    N      = in_sizes[2];             // 1024 tokens
    const int    nocc   = N * NLOG;                // 525312
    const int    nh8    = N * HDIM / 4;            // 196608 packed fp8 u32

    // ws layout (u32/f32 elements): counts[PADV] cursor[PADV] pay[nocc]
    //                               hb[nh8] logits[nocc] loss[N]
    unsigned int* counts     = (unsigned int*)d_ws;
    unsigned int* cursor     = counts + PADV;
    unsigned int* sorted_pay = cursor + PADV;
    unsigned int* hb         = sorted_pay + nocc;
    float*        logits     = (float*)(hb + nh8);
    float*        loss       = logits + nocc;
    const size_t  need_bytes = (size_t)(2 * PADV + 2 * nocc + nh8 + N) * 4;

    if (ws_size < need_bytes) {
        // fallback: direct gather path (R1)
        float* ws = (float*)d_ws;
        nce_token_kernel<<<N, 512, 0, stream>>>(h, W, target, noise, ws);
        reduce_mean_kernel<<<1, 256, 0, stream>>>(ws, out, N);
        return;
    }

    (void)hipMemsetAsync(counts, 0, (size_t)PADV * 4, stream);
    pre_kernel<<<CONVB + HISTB, 256, 0, stream>>>(h, hb, target, noise,
                                                  counts, N, nh8);
    scan_kernel<<<1, 1024, 0, stream>>>(counts, cursor);
    scatter_kernel<<<512, 256, 0, stream>>>(target, noise, cursor, sorted_pay, N);
    const int gblocks = (VOCAB + (GTPB / 64) - 1) / (GTPB / 64);
    gather_run_kernel<<<gblocks, GTPB, 0, stream>>>(hb, W, counts, cursor,
                                                    sorted_pay, logits);
    softmax_loss_kernel<<<N, 256, 0, stream>>>(logits, loss);
    reduce_mean_kernel<<<1, 256, 0, stream>>>(loss, out, N);
}